// Round 1
// baseline (978.618 us; speedup 1.0000x reference)
//
#include <hip/hip_runtime.h>
#include <hip/hip_bf16.h>
#include <hip/hip_fp16.h>

#define STEP 0.01f
#define D 64
#define NUM_LAYERS 10

union H4 { uint2 u; __half h[4]; };
union H8 { uint4 u; __half2 h2[4]; __half h[8]; };

// ---------------- CSR build ----------------

__global__ void k_setup(float* __restrict__ degf, int* __restrict__ degd, int N) {
    int n = blockIdx.x * blockDim.x + threadIdx.x;
    if (n < N) { degf[n] = 1.0f; degd[n] = 0; }
}

__global__ void k_deg2(const int* __restrict__ ei, float* __restrict__ degf,
                       int* __restrict__ degd, int E) {
    int e = blockIdx.x * blockDim.x + threadIdx.x;
    if (e < E) {
        unsafeAtomicAdd(&degf[ei[e]], 1.0f);   // out-degree (src)
        atomicAdd(&degd[ei[E + e]], 1);        // in-degree (dst)
    }
}

__global__ __launch_bounds__(1024) void k_scan(
        const int* __restrict__ degd, const float* __restrict__ degf,
        int* __restrict__ row_ptr, int* __restrict__ cursor,
        float* __restrict__ invdeg, int N, int E) {
    __shared__ int part[1024];
    int tid = threadIdx.x;
    int chunk = (N + 1023) / 1024;
    int lo = tid * chunk, hi = min(lo + chunk, N);
    int s = 0;
    for (int i = lo; i < hi; ++i) s += degd[i];
    part[tid] = s;
    __syncthreads();
    for (int off = 1; off < 1024; off <<= 1) {
        int v = (tid >= off) ? part[tid - off] : 0;
        __syncthreads();
        part[tid] += v;
        __syncthreads();
    }
    int base = (tid == 0) ? 0 : part[tid - 1];
    for (int i = lo; i < hi; ++i) {
        row_ptr[i] = base;
        cursor[i] = base;
        base += degd[i];
        invdeg[i] = 1.0f / degf[i];
    }
    if (tid == 1023) row_ptr[N] = E;
}

__global__ void k_scatter(const int* __restrict__ ei, int* __restrict__ cursor,
                          int* __restrict__ col, int E) {
    int e = blockIdx.x * blockDim.x + threadIdx.x;
    if (e < E) {
        int pos = atomicAdd(&cursor[ei[E + e]], 1);
        col[pos] = ei[e];
    }
}

// ---------------- init: A->fp16 + y=2Ax+b + emit pre-weighted fp16 msgs ----------------

__global__ __launch_bounds__(256) void k_init(
        const float* __restrict__ A, const float* __restrict__ b,
        const float* __restrict__ x, const float* __restrict__ invdeg,
        __half* __restrict__ Ah, __half2* __restrict__ msg,
        float* __restrict__ vw, float* __restrict__ x0, int N) {
    __shared__ __align__(16) float sx[D];
    __shared__ float syv[D];
    int n = blockIdx.x, t = threadIdx.x;
    int lane = t & 63, w = t >> 6, colgrp = lane & 15;
    if (t < D) sx[t] = x[(size_t)n * D + t];
    __syncthreads();
    const float* An = A + (size_t)n * D * D;
    __half* Ahn = Ah + (size_t)n * D * D;
    float4 xr = ((const float4*)sx)[colgrp];
    int rbase = w * 16 + (lane >> 4);
#pragma unroll
    for (int g = 0; g < 4; ++g) {
        int row = rbase + g * 4;
        float4 a = ((const float4*)(An + (size_t)row * D))[colgrp];
        H4 pk;
        pk.h[0] = __float2half(a.x);
        pk.h[1] = __float2half(a.y);
        pk.h[2] = __float2half(a.z);
        pk.h[3] = __float2half(a.w);
        ((uint2*)(Ahn + (size_t)row * D))[colgrp] = pk.u;
        float p = a.x * xr.x + a.y * xr.y + a.z * xr.z + a.w * xr.w;
        p += __shfl_xor(p, 1);
        p += __shfl_xor(p, 2);
        p += __shfl_xor(p, 4);
        p += __shfl_xor(p, 8);
        if (colgrp == 0) syv[row] = 2.0f * p + b[(size_t)n * D + row];
    }
    __syncthreads();
    if (t < D) {
        float wd = invdeg[n];
        float xv = sx[t];
        float yv = syv[t];
        msg[(size_t)n * D + t] = __floats2half2_rn((xv - STEP * yv) * wd, yv * wd);
        x0[(size_t)n * D + t] = xv;
        if (t == 0) vw[n] = wd;
    }
}

// ---------------- fused layer (v2: front-loaded prefetch, 2 barriers, direct emit) ----------------

__global__ __launch_bounds__(256) void k_layer(
        const __half* __restrict__ Ah,
        const int* __restrict__ row_ptr, const int* __restrict__ col,
        const __half2* __restrict__ msg, const float* __restrict__ vw,
        const float* __restrict__ invdeg,
        __half2* __restrict__ msgn, float* __restrict__ vwn,
        float* __restrict__ x0, float* __restrict__ xout,
        int last_idx, float comm, int N) {
    __shared__ float su[4][D];
    __shared__ float sy[4][D];
    __shared__ float sv[4];
    __shared__ __align__(16) float sdx[D];
    __shared__ float sun[D];
    __shared__ float sytot[D];

    int n = blockIdx.x, t = threadIdx.x;
    int lane = t & 63, w = t >> 6;
    int j = lane >> 4, q4 = lane & 15;

    // ---- prefetch: everything that does NOT depend on the gather ----
    // Issued before phase 1 so their latency hides under the edge gather;
    // the vmcnt(0) drain at barrier 1 finds them already (or nearly) done.
    int rs = row_ptr[n], re = row_ptr[n + 1];
    const uint4* Ahp = (const uint4*)(Ah + (size_t)n * D * D);
    H8 a0, a1;
    a0.u = Ahp[t];            // 8 KB/block A-tile: issued here, used in phase 3
    a1.u = Ahp[256 + t];
    float invd = invdeg[n];
    float2 self = {0.0f, 0.0f};
    float x0v = 0.0f, vwself = 0.0f;
    if (w == 0) {             // wave-uniform branch: no divergence cost
        size_t off = (size_t)n * D + lane;
        self = __half22float2(msg[off]);
        x0v = x0[off];
        vwself = vw[n];
    }

    // ---- phase 1: gather — 4 edges per wave-pass, one uint4 (4x half2 (u,y)) per lane
    float4 au = {0.f, 0.f, 0.f, 0.f}, ay = {0.f, 0.f, 0.f, 0.f};
    float av = 0.0f;
    for (int base = rs + w * 4; base < re; base += 16) {
        int e = base + j;
        if (e < re) {
            int s = col[e];
            H8 m;
            m.u = ((const uint4*)(msg + (size_t)s * D))[q4];
            float2 f0 = __half22float2(m.h2[0]);
            float2 f1 = __half22float2(m.h2[1]);
            float2 f2 = __half22float2(m.h2[2]);
            float2 f3 = __half22float2(m.h2[3]);
            au.x += f0.x; ay.x += f0.y;
            au.y += f1.x; ay.y += f1.y;
            au.z += f2.x; ay.z += f2.y;
            au.w += f3.x; ay.w += f3.y;
            if (q4 == 0) av += vw[s];
        }
    }
    // reduce across the 4 edge slots (lanes xor 16, 32)
    au.x += __shfl_xor(au.x, 16); au.y += __shfl_xor(au.y, 16);
    au.z += __shfl_xor(au.z, 16); au.w += __shfl_xor(au.w, 16);
    au.x += __shfl_xor(au.x, 32); au.y += __shfl_xor(au.y, 32);
    au.z += __shfl_xor(au.z, 32); au.w += __shfl_xor(au.w, 32);
    ay.x += __shfl_xor(ay.x, 16); ay.y += __shfl_xor(ay.y, 16);
    ay.z += __shfl_xor(ay.z, 16); ay.w += __shfl_xor(ay.w, 16);
    ay.x += __shfl_xor(ay.x, 32); ay.y += __shfl_xor(ay.y, 32);
    ay.z += __shfl_xor(ay.z, 32); ay.w += __shfl_xor(ay.w, 32);
    av += __shfl_xor(av, 16);
    av += __shfl_xor(av, 32);
    if (j == 0) {
        ((float4*)su[w])[q4] = au;
        ((float4*)sy[w])[q4] = ay;
        if (q4 == 0) sv[w] = av;
    }
    __syncthreads();

    // ---- phase 2: combine + self term; x1 = un/vn; dx = x1 - x0 (all inputs prefetched)
    if (w == 0) {
        size_t off = (size_t)n * D + lane;
        float ut = su[0][lane] + su[1][lane] + su[2][lane] + su[3][lane] + self.x;
        float yt = sy[0][lane] + sy[1][lane] + sy[2][lane] + sy[3][lane] + self.y;
        float vt = sv[0] + sv[1] + sv[2] + sv[3] + vwself;
        float x1 = ut / vt;
        sdx[lane] = x1 - x0v;
        x0[off] = x1;
        if (xout) xout[off] = x1;
        sun[lane] = ut;
        sytot[lane] = yt;
        if (lane == 0) vwn[n] = vt * invd;
        if (xout && n == 0 && lane == 0) xout[last_idx] = comm;
    }
    __syncthreads();

    // ---- phase 3: yn = yt + 2*A@dx using the prefetched A-tile; emit messages directly
    {
        int cb = (t & 7) * 8;
        int r0 = t >> 3;
        float p0 = 0.0f, p1 = 0.0f;
#pragma unroll
        for (int jj = 0; jj < 8; ++jj) {
            float dv = sdx[cb + jj];
            p0 += __half2float(a0.h[jj]) * dv;
            p1 += __half2float(a1.h[jj]) * dv;
        }
        p0 += __shfl_xor(p0, 1); p1 += __shfl_xor(p1, 1);
        p0 += __shfl_xor(p0, 2); p1 += __shfl_xor(p1, 2);
        p0 += __shfl_xor(p0, 4); p1 += __shfl_xor(p1, 4);
        if ((lane & 7) == 0) {
            float yn0 = sytot[r0]      + 2.0f * p0;
            float yn1 = sytot[32 + r0] + 2.0f * p1;
            msgn[(size_t)n * D + r0] =
                __floats2half2_rn((sun[r0] - STEP * yn0) * invd, yn0 * invd);
            msgn[(size_t)n * D + 32 + r0] =
                __floats2half2_rn((sun[32 + r0] - STEP * yn1) * invd, yn1 * invd);
        }
    }
}

// ---------------- host launcher ----------------

extern "C" void kernel_launch(void* const* d_in, const int* in_sizes, int n_in,
                              void* d_out, int out_size, void* d_ws, size_t ws_size,
                              hipStream_t stream) {
    const float* A  = (const float*)d_in[0];
    const float* b  = (const float*)d_in[1];
    const float* x  = (const float*)d_in[2];
    const int*   ei = (const int*)d_in[3];

    const int N = in_sizes[1] / D;        // b is [N, D]
    const int E = in_sizes[3] / 2;        // edge_index is [2, E]
    const size_t ND = (size_t)N * D;

    char* ws = (char*)d_ws;
    __half* Ah = (__half*)ws;                               // N*D*D halves
    __half2* msg0 = (__half2*)(ws + ND * D * sizeof(__half));
    __half2* msg1 = msg0 + ND;
    float* x0   = (float*)(msg1 + ND);
    float* vw0  = x0 + ND;
    float* vw1  = vw0 + N;
    float* invdeg = vw1 + N;
    float* degf = invdeg + N;
    int* degd    = (int*)(degf + N);
    int* row_ptr = degd + N;
    int* cursor  = row_ptr + N + 4;
    int* col     = cursor + N;

    k_setup<<<(N + 255) / 256, 256, 0, stream>>>(degf, degd, N);
    k_deg2<<<(E + 255) / 256, 256, 0, stream>>>(ei, degf, degd, E);
    k_scan<<<1, 1024, 0, stream>>>(degd, degf, row_ptr, cursor, invdeg, N, E);
    k_scatter<<<(E + 255) / 256, 256, 0, stream>>>(ei, cursor, col, E);
    k_init<<<N, 256, 0, stream>>>(A, b, x, invdeg, Ah, msg0, vw0, x0, N);

    float comm = (float)(3 * NUM_LAYERS * E);
    __half2 *mc = msg0, *mn = msg1;
    float *vc = vw0, *vn = vw1;
    for (int l = 0; l < NUM_LAYERS; ++l) {
        float* xout = (l == NUM_LAYERS - 1) ? (float*)d_out : nullptr;
        k_layer<<<N, 256, 0, stream>>>(Ah, row_ptr, col, mc, vc, invdeg,
                                       mn, vn, x0, xout, out_size - 1, comm, N);
        __half2* tm = mc; mc = mn; mn = tm;
        float* tv = vc; vc = vn; vn = tv;
    }
}

// Round 2
// 960.610 us; speedup vs baseline: 1.0187x; 1.0187x over previous
//
#include <hip/hip_runtime.h>
#include <hip/hip_bf16.h>
#include <hip/hip_fp16.h>

#define STEP 0.01f
#define D 64
#define NUM_LAYERS 10

union H4 { uint2 u; __half h[4]; };
union H8 { uint4 u; __half2 h2[4]; __half h[8]; };

// ---------------- CSR build ----------------

__global__ void k_setup(float* __restrict__ degf, int* __restrict__ degd, int N) {
    int n = blockIdx.x * blockDim.x + threadIdx.x;
    if (n < N) { degf[n] = 1.0f; degd[n] = 0; }
}

__global__ void k_deg2(const int* __restrict__ ei, float* __restrict__ degf,
                       int* __restrict__ degd, int E) {
    int e = blockIdx.x * blockDim.x + threadIdx.x;
    if (e < E) {
        unsafeAtomicAdd(&degf[ei[e]], 1.0f);   // out-degree (src)
        atomicAdd(&degd[ei[E + e]], 1);        // in-degree (dst)
    }
}

__global__ __launch_bounds__(1024) void k_scan(
        const int* __restrict__ degd, const float* __restrict__ degf,
        int* __restrict__ row_ptr, int* __restrict__ cursor,
        float* __restrict__ invdeg, int N, int E) {
    __shared__ int part[1024];
    int tid = threadIdx.x;
    int chunk = (N + 1023) / 1024;
    int lo = tid * chunk, hi = min(lo + chunk, N);
    int s = 0;
    for (int i = lo; i < hi; ++i) s += degd[i];
    part[tid] = s;
    __syncthreads();
    for (int off = 1; off < 1024; off <<= 1) {
        int v = (tid >= off) ? part[tid - off] : 0;
        __syncthreads();
        part[tid] += v;
        __syncthreads();
    }
    int base = (tid == 0) ? 0 : part[tid - 1];
    for (int i = lo; i < hi; ++i) {
        row_ptr[i] = base;
        cursor[i] = base;
        base += degd[i];
        invdeg[i] = 1.0f / degf[i];
    }
    if (tid == 1023) row_ptr[N] = E;
}

__global__ void k_scatter(const int* __restrict__ ei, int* __restrict__ cursor,
                          int* __restrict__ col, int E) {
    int e = blockIdx.x * blockDim.x + threadIdx.x;
    if (e < E) {
        int pos = atomicAdd(&cursor[ei[E + e]], 1);
        col[pos] = ei[e];
    }
}

// ---------------- init: A->fp16 + y=2Ax+b + emit pre-weighted fp16 msgs ----------------

__global__ __launch_bounds__(256) void k_init(
        const float* __restrict__ A, const float* __restrict__ b,
        const float* __restrict__ x, const float* __restrict__ invdeg,
        __half* __restrict__ Ah, __half2* __restrict__ msg,
        float* __restrict__ vw, float* __restrict__ x0, int N) {
    __shared__ __align__(16) float sx[D];
    __shared__ float syv[D];
    int n = blockIdx.x, t = threadIdx.x;
    int lane = t & 63, w = t >> 6, colgrp = lane & 15;
    if (t < D) sx[t] = x[(size_t)n * D + t];
    __syncthreads();
    const float* An = A + (size_t)n * D * D;
    __half* Ahn = Ah + (size_t)n * D * D;
    float4 xr = ((const float4*)sx)[colgrp];
    int rbase = w * 16 + (lane >> 4);
#pragma unroll
    for (int g = 0; g < 4; ++g) {
        int row = rbase + g * 4;
        float4 a = ((const float4*)(An + (size_t)row * D))[colgrp];
        H4 pk;
        pk.h[0] = __float2half(a.x);
        pk.h[1] = __float2half(a.y);
        pk.h[2] = __float2half(a.z);
        pk.h[3] = __float2half(a.w);
        ((uint2*)(Ahn + (size_t)row * D))[colgrp] = pk.u;
        float p = a.x * xr.x + a.y * xr.y + a.z * xr.z + a.w * xr.w;
        p += __shfl_xor(p, 1);
        p += __shfl_xor(p, 2);
        p += __shfl_xor(p, 4);
        p += __shfl_xor(p, 8);
        if (colgrp == 0) syv[row] = 2.0f * p + b[(size_t)n * D + row];
    }
    __syncthreads();
    if (t < D) {
        float wd = invdeg[n];
        float xv = sx[t];
        float yv = syv[t];
        msg[(size_t)n * D + t] = __floats2half2_rn((xv - STEP * yv) * wd, yv * wd);
        x0[(size_t)n * D + t] = xv;
        if (t == 0) vw[n] = wd;
    }
}

// ---------------- fused layer (v3: one WAVE per node, no barriers, no LDS) ----------------

__global__ __launch_bounds__(256) void k_layer(
        const __half* __restrict__ Ah,
        const int* __restrict__ row_ptr, const int* __restrict__ col,
        const __half2* __restrict__ msg, const float* __restrict__ vw,
        const float* __restrict__ invdeg,
        __half2* __restrict__ msgn, float* __restrict__ vwn,
        float* __restrict__ x0, float* __restrict__ xout,
        int last_idx, float comm, int N) {
    int t = threadIdx.x;
    int lane = t & 63, w = t >> 6;
    int n = blockIdx.x * 4 + w;      // one wave per node; wave-uniform guard
    if (n >= N) return;

    int j = lane >> 4, q4 = lane & 15;
    int rs = row_ptr[n], re = row_ptr[n + 1];

    // prefetch the full 8KB A-tile into 32 VGPRs (latency hides under gather)
    // round k, lane l -> Ah bytes [k*1024 + l*16 .. +16): row (l>>3)+8k, cols (l&7)*8..+7
    const uint4* Ap = (const uint4*)(Ah + (size_t)n * D * D);
    uint4 a[8];
#pragma unroll
    for (int k = 0; k < 8; ++k) a[k] = Ap[lane + 64 * k];

    // self terms (per-dim: lane d owns dim d)
    size_t off = (size_t)n * D + lane;
    float2 msf = __half22float2(msg[off]);
    float x0v = x0[off];
    float vwn_self = vw[n];
    float invd = invdeg[n];

    // ---- gather: 8 edges per pass (2 per 16-lane group), loads issued before accumulates
    float4 au = {0.f, 0.f, 0.f, 0.f}, ay = {0.f, 0.f, 0.f, 0.f};
    float av = 0.0f;
    for (int base = rs; base < re; base += 8) {
        int e0 = base + (j << 1), e1 = e0 + 1;
        bool b0 = e0 < re, b1 = e1 < re;
        int s0 = 0, s1 = 0;
        if (b0) s0 = col[e0];
        if (b1) s1 = col[e1];
        H8 m0, m1;
        m0.u = make_uint4(0u, 0u, 0u, 0u);
        m1.u = make_uint4(0u, 0u, 0u, 0u);
        float w0 = 0.f, w1 = 0.f;
        if (b0) m0.u = ((const uint4*)(msg + (size_t)s0 * D))[q4];
        if (b1) m1.u = ((const uint4*)(msg + (size_t)s1 * D))[q4];
        if (b0 && q4 == 0) w0 = vw[s0];
        if (b1 && q4 == 0) w1 = vw[s1];
        float2 f0 = __half22float2(m0.h2[0]);
        float2 f1 = __half22float2(m0.h2[1]);
        float2 f2 = __half22float2(m0.h2[2]);
        float2 f3 = __half22float2(m0.h2[3]);
        au.x += f0.x; ay.x += f0.y;
        au.y += f1.x; ay.y += f1.y;
        au.z += f2.x; ay.z += f2.y;
        au.w += f3.x; ay.w += f3.y;
        f0 = __half22float2(m1.h2[0]);
        f1 = __half22float2(m1.h2[1]);
        f2 = __half22float2(m1.h2[2]);
        f3 = __half22float2(m1.h2[3]);
        au.x += f0.x; ay.x += f0.y;
        au.y += f1.x; ay.y += f1.y;
        au.z += f2.x; ay.z += f2.y;
        au.w += f3.x; ay.w += f3.y;
        av += w0 + w1;
    }
    // sum the 4 edge groups (lanes xor 16, 32); every lane ends with the group-total
    au.x += __shfl_xor(au.x, 16); au.y += __shfl_xor(au.y, 16);
    au.z += __shfl_xor(au.z, 16); au.w += __shfl_xor(au.w, 16);
    au.x += __shfl_xor(au.x, 32); au.y += __shfl_xor(au.y, 32);
    au.z += __shfl_xor(au.z, 32); au.w += __shfl_xor(au.w, 32);
    ay.x += __shfl_xor(ay.x, 16); ay.y += __shfl_xor(ay.y, 16);
    ay.z += __shfl_xor(ay.z, 16); ay.w += __shfl_xor(ay.w, 16);
    ay.x += __shfl_xor(ay.x, 32); ay.y += __shfl_xor(ay.y, 32);
    ay.z += __shfl_xor(ay.z, 32); ay.w += __shfl_xor(ay.w, 32);
    av += __shfl_xor(av, 16);
    av += __shfl_xor(av, 32);
    av = __shfl(av, 0);              // only q4==0 lanes held vw sums; lane 0 has total

    // ---- transpose float4-per-group -> scalar per lane (lane d owns dim d)
    int src = lane >> 2, c = lane & 3;
    float ua = __shfl(au.x, src), ub = __shfl(au.y, src),
          uc = __shfl(au.z, src), ud = __shfl(au.w, src);
    float ya = __shfl(ay.x, src), yb = __shfl(ay.y, src),
          yc = __shfl(ay.z, src), yd = __shfl(ay.w, src);
    float ut = (c & 2) ? ((c & 1) ? ud : uc) : ((c & 1) ? ub : ua);
    float yt = (c & 2) ? ((c & 1) ? yd : yc) : ((c & 1) ? yb : ya);
    ut += msf.x;
    yt += msf.y;

    float vt = av + vwn_self;
    float rvt = __builtin_amdgcn_rcpf(vt);
    float x1 = ut * rvt;
    float dx = x1 - x0v;
    x0[off] = x1;
    if (xout) xout[off] = x1;
    if (lane == 0) vwn[n] = vt * invd;
    if (xout && n == 0 && lane == 0) xout[last_idx] = comm;

    // ---- matvec: lane l handles cols (l&7)*8..+7 of rows (l>>3)+8k
    int cb = (lane & 7) * 8;
    float dxv[8];
#pragma unroll
    for (int jj = 0; jj < 8; ++jj) dxv[jj] = __shfl(dx, cb + jj);

    float pk[8];
#pragma unroll
    for (int k = 0; k < 8; ++k) {
        H8 aa; aa.u = a[k];
        float p = 0.f;
#pragma unroll
        for (int jj = 0; jj < 8; ++jj)
            p += __half2float(aa.h[jj]) * dxv[jj];
        p += __shfl_xor(p, 1);
        p += __shfl_xor(p, 2);
        p += __shfl_xor(p, 4);
        pk[k] = p;                    // all 8 lanes of the row-group hold row (l>>3)+8k
    }
    // lane d wants row d = (d&7) + 8*(d>>3): pull pk[k] from lane (d&7)*8, select k=d>>3
    int srcg = (lane & 7) * 8;
    float pr[8];
#pragma unroll
    for (int k = 0; k < 8; ++k) pr[k] = __shfl(pk[k], srcg);
    int kk = lane >> 3;
    float prow = (kk & 4) ? ((kk & 2) ? ((kk & 1) ? pr[7] : pr[6])
                                      : ((kk & 1) ? pr[5] : pr[4]))
                          : ((kk & 2) ? ((kk & 1) ? pr[3] : pr[2])
                                      : ((kk & 1) ? pr[1] : pr[0]));
    float yn = yt + 2.0f * prow;
    // fully-coalesced 256B wave store of next-layer message
    msgn[off] = __floats2half2_rn((ut - STEP * yn) * invd, yn * invd);
}

// ---------------- host launcher ----------------

extern "C" void kernel_launch(void* const* d_in, const int* in_sizes, int n_in,
                              void* d_out, int out_size, void* d_ws, size_t ws_size,
                              hipStream_t stream) {
    const float* A  = (const float*)d_in[0];
    const float* b  = (const float*)d_in[1];
    const float* x  = (const float*)d_in[2];
    const int*   ei = (const int*)d_in[3];

    const int N = in_sizes[1] / D;        // b is [N, D]
    const int E = in_sizes[3] / 2;        // edge_index is [2, E]
    const size_t ND = (size_t)N * D;

    char* ws = (char*)d_ws;
    __half* Ah = (__half*)ws;                               // N*D*D halves
    __half2* msg0 = (__half2*)(ws + ND * D * sizeof(__half));
    __half2* msg1 = msg0 + ND;
    float* x0   = (float*)(msg1 + ND);
    float* vw0  = x0 + ND;
    float* vw1  = vw0 + N;
    float* invdeg = vw1 + N;
    float* degf = invdeg + N;
    int* degd    = (int*)(degf + N);
    int* row_ptr = degd + N;
    int* cursor  = row_ptr + N + 4;
    int* col     = cursor + N;

    k_setup<<<(N + 255) / 256, 256, 0, stream>>>(degf, degd, N);
    k_deg2<<<(E + 255) / 256, 256, 0, stream>>>(ei, degf, degd, E);
    k_scan<<<1, 1024, 0, stream>>>(degd, degf, row_ptr, cursor, invdeg, N, E);
    k_scatter<<<(E + 255) / 256, 256, 0, stream>>>(ei, cursor, col, E);
    k_init<<<N, 256, 0, stream>>>(A, b, x, invdeg, Ah, msg0, vw0, x0, N);

    float comm = (float)(3 * NUM_LAYERS * E);
    __half2 *mc = msg0, *mn = msg1;
    float *vc = vw0, *vn = vw1;
    for (int l = 0; l < NUM_LAYERS; ++l) {
        float* xout = (l == NUM_LAYERS - 1) ? (float*)d_out : nullptr;
        k_layer<<<(N + 3) / 4, 256, 0, stream>>>(Ah, row_ptr, col, mc, vc, invdeg,
                                                 mn, vn, x0, xout, out_size - 1, comm, N);
        __half2* tm = mc; mc = mn; mn = tm;
        float* tv = vc; vc = vn; vn = tv;
    }
}